// Round 12
// baseline (165.668 us; speedup 1.0000x reference)
//
#include <hip/hip_runtime.h>

// out = L@(X@W1 + X^2@W2) + X@W1 + b1 + b2
// Y (bf16, ws) = X@W1 + X^2@W2 ; Z = X@W1 + b1 + b2.
// Pipeline:
//   prep (tiny: gcursor/ovf init + W1,W2 -> bf16 TRANSPOSED [col][k] +
//   bsum=b1+b2) -> node_transform (MFMA 16x16x32; B-fragments load as ONE
//   16B vector each from Wb*t -- r11's 128 scalar stride-64 loads + 128
//   f2bf per thread removed) -> bin_scatter (512 threads, LDS chunk-sort,
//   single-atomic-pass, register-carried edges) -> bucket_gather_quads
//   (2 blocks/bucket row halves; raw chunk staged to LDS once -- packed
//   read ONCE per block; in-LDS counting sort; uint2 = 4x bf16 gather
//   loads; register acc; float4 out RMW; +64 drain-role blocks replace the
//   separate overflow_scatter launch).
//
// MEASURED LESSONS:
//  r3/r4: LDS fp32 atomicAdd (plain AND unsafeAtomicAdd -- identical
//    codegen) ~139 cyc/op fully serialized on gfx950. No LDS fp atomics
//    in hot accumulation; counting-sort + register acc wins 13x.
//  r6/r10: per-edge GLOBAL atomics lose BOTH ways -- hot-line atomic-rtn
//    (r6: 83us) AND spread no-return (r10: +25us). Keep per-edge counting
//    in LDS.
//  r8/r9: NT+scatter fusion neutral-negative; 512-thread 1-block/bucket
//    gather slower than 2x256.
//  r11: bin_scatter 256->512 threads (occupancy 12%->~25%) = -5.5us total.

#define ROWS_PER_BUCKET 128
#define ROW_SHIFT 7
#define NBUCK_PAD 784        // 196*4, covers nbuck=782
#define SCAN_T 196
#define CAP 2048             // per-bucket fixed capacity
#define CHUNK 4096           // edges per bin_scatter block
#define SCT 512              // bin_scatter threads
#define EPT 8                // CHUNK / SCT edges per thread
#define MAXB 2048            // max bucket-chunk held in LDS by gather
#define OVF_BLOCKS 64        // drain-role blocks appended to gather grid
#define COL_BITS 17
#define COL_MASK 0x1FFFF
#define OVF_CAP 65536

typedef __attribute__((ext_vector_type(8))) short bf16x8;
typedef __attribute__((ext_vector_type(4))) float f32x4;

__device__ __forceinline__ unsigned short f2bf(float x) {
    unsigned u = __float_as_uint(x);
    unsigned r = (u + 0x7FFFu + ((u >> 16) & 1u)) >> 16;   // RNE
    return (unsigned short)r;
}
__device__ __forceinline__ float bf2f(unsigned short h) {
    return __uint_as_float(((unsigned)h) << 16);
}

// Tiny setup kernel, 16 blocks x 256 = 4096 threads (one W element each):
//  - gcursor / ovf_count init (guarded; null in fallback path)
//  - Wb{1,2}t[col*64+k] = bf16(W{1,2}[k*64+col])  (coalesced 2B writes)
//  - bsum = b1 + b2
__global__ __launch_bounds__(256) void prep(
    const float* __restrict__ W1, const float* __restrict__ W2,
    const float* __restrict__ b1, const float* __restrict__ b2,
    unsigned short* __restrict__ Wb1t, unsigned short* __restrict__ Wb2t,
    float* __restrict__ bsum, int* __restrict__ gcursor,
    int* __restrict__ ovf_count)
{
    int i = blockIdx.x * 256 + threadIdx.x;
    if (gcursor) {
        if (i < NBUCK_PAD) gcursor[i] = i * CAP;
        if (i == 0) *ovf_count = 0;
    }
    if (i < 64) bsum[i] = b1[i] + b2[i];
    if (i < 4096) {
        int col = i >> 6, k = i & 63;
        Wb1t[col * 64 + k] = f2bf(W1[k * 64 + col]);
        Wb2t[col * 64 + k] = f2bf(W2[k * 64 + col]);
    }
}

// MFMA node transform: block = 256 threads = 4 waves, 128 rows/block.
// Wave w: rows base+w*32 .. +31. Frags: A row = lane&15, k = 8*(lane>>4)+j;
// B col = lane&15, same k; D row = 4*(lane>>4)+i, col = lane&15.
// B-fragments: ONE bf16x8 (16B) vector load each from transposed Wb*t.
__global__ __launch_bounds__(256) void node_transform(
    const float* __restrict__ X, const unsigned short* __restrict__ Wb1t,
    const unsigned short* __restrict__ Wb2t, const float* __restrict__ bsum,
    unsigned short* __restrict__ Yb, float* __restrict__ Z, int n_nodes)
{
    const int tid = threadIdx.x;
    const int lane = tid & 63;
    const int wave = tid >> 6;          // 0..3
    const int lg = lane >> 4;           // 0..3
    const int lr = lane & 15;

    const int base = blockIdx.x * 128 + wave * 32;

    // ---- B fragments: vector loads from transposed bf16 W ----
    bf16x8 bw1[2][4];
    bf16x8 bw2[2][4];
#pragma unroll
    for (int ks = 0; ks < 2; ++ks) {
#pragma unroll
        for (int cf = 0; cf < 4; ++cf) {
            const int off = (cf * 16 + lr) * 64 + ks * 32 + lg * 8;
            bw1[ks][cf] = *(const bf16x8*)(Wb1t + off);
            bw2[ks][cf] = *(const bf16x8*)(Wb2t + off);
        }
    }

    f32x4 acc1[2][4];
    f32x4 acc2[2][4];
#pragma unroll
    for (int rf = 0; rf < 2; ++rf)
#pragma unroll
        for (int cf = 0; cf < 4; ++cf) {
            acc1[rf][cf] = (f32x4){0.f, 0.f, 0.f, 0.f};
            acc2[rf][cf] = (f32x4){0.f, 0.f, 0.f, 0.f};
        }

    // ---- main: load A (X rows, coalesced 32B/lane), square, MFMA ----
#pragma unroll
    for (int rf = 0; rf < 2; ++rf) {
        const int row = base + rf * 16 + lr;
        const bool rok = row < n_nodes;
        const float* xp = X + (size_t)row * 64 + lg * 8;
#pragma unroll
        for (int ks = 0; ks < 2; ++ks) {
            float xv[8];
            if (rok) {
                float4 v0 = *(const float4*)(xp + ks * 32);
                float4 v1 = *(const float4*)(xp + ks * 32 + 4);
                xv[0] = v0.x; xv[1] = v0.y; xv[2] = v0.z; xv[3] = v0.w;
                xv[4] = v1.x; xv[5] = v1.y; xv[6] = v1.z; xv[7] = v1.w;
            } else {
#pragma unroll
                for (int j = 0; j < 8; ++j) xv[j] = 0.f;
            }
            bf16x8 a, q;
#pragma unroll
            for (int j = 0; j < 8; ++j) {
                a[j] = (short)f2bf(xv[j]);
                float s = xv[j] * xv[j];
                q[j] = (short)f2bf(s);
            }
#pragma unroll
            for (int cf = 0; cf < 4; ++cf) {
                acc1[rf][cf] = __builtin_amdgcn_mfma_f32_16x16x32_bf16(
                    a, bw1[ks][cf], acc1[rf][cf], 0, 0, 0);
                acc2[rf][cf] = __builtin_amdgcn_mfma_f32_16x16x32_bf16(
                    q, bw2[ks][cf], acc2[rf][cf], 0, 0, 0);
            }
        }
    }

    // ---- epilogue ----
    float bsv[4];
#pragma unroll
    for (int cf = 0; cf < 4; ++cf)
        bsv[cf] = bsum[cf * 16 + lr];

#pragma unroll
    for (int rf = 0; rf < 2; ++rf) {
#pragma unroll
        for (int i = 0; i < 4; ++i) {
            const int row = base + rf * 16 + lg * 4 + i;
            if (row < n_nodes) {
#pragma unroll
                for (int cf = 0; cf < 4; ++cf) {
                    const float v1 = acc1[rf][cf][i];
                    const float y = v1 + acc2[rf][cf][i];
                    const float z = v1 + bsv[cf];
                    Yb[(size_t)row * 64 + cf * 16 + lr] = f2bf(y);
                    Z[(size_t)row * 64 + cf * 16 + lr] = z;
                }
            }
        }
    }
}

// ---------------- fixed-capacity bucket build ----------------

// LDS-staged binned scatter, single-atomic-pass at 512 threads (r11):
//  pass 1: read each edge ONCE; the LDS histogram atomic's return value is
//          the in-bucket position; edge data stays in registers (EPT=8
//          statically-indexed -> VGPRs).
//  scan:   per-wave __shfl_up inclusive scan + 8-entry cross-wave fixup.
//  stage:  int2 LDS write at lstart[b]+p, no second atomic.
//  out:    i-ordered walk -> coalesced runs into packed[] per bucket.
__global__ __launch_bounds__(512) void bin_scatter(
    const int* __restrict__ rows, const int* __restrict__ cols,
    const float* __restrict__ vals, int* __restrict__ gcursor,
    int2* __restrict__ packed, int* __restrict__ ovf_count,
    int4* __restrict__ ovf, int n_edges) {
    __shared__ int lcount[NBUCK_PAD];              // 3.1 KB
    __shared__ int lstart[NBUCK_PAD];              // 3.1 KB
    __shared__ int gbase[NBUCK_PAD];               // 3.1 KB
    __shared__ int2 sxy[CHUNK];                    // 32 KB
    __shared__ unsigned short sbk[CHUNK];          // 8 KB
    __shared__ int wsum[8];

    int tid = threadIdx.x;
    int eb0 = blockIdx.x * CHUNK;
    int cnt = min(CHUNK, n_edges - eb0);

    for (int k = tid; k < NBUCK_PAD; k += SCT) lcount[k] = 0;
    __syncthreads();

    // pass 1: single read + histogram with position capture
    int eb_[EPT], ep_[EPT], ex_[EPT], ey_[EPT];
#pragma unroll
    for (int t = 0; t < EPT; ++t) {
        int i = tid + SCT * t;
        if (i < cnt) {
            int r = rows[eb0 + i];
            int b = r >> ROW_SHIFT;
            eb_[t] = b;
            ep_[t] = atomicAdd(&lcount[b], 1);
            ex_[t] = ((r & (ROWS_PER_BUCKET - 1)) << COL_BITS) | cols[eb0 + i];
            ey_[t] = __float_as_int(vals[eb0 + i]);
        } else {
            eb_[t] = -1; ep_[t] = 0; ex_[t] = 0; ey_[t] = 0;
        }
    }
    __syncthreads();

    // exclusive scan of lcount: thread t<SCAN_T owns buckets 4t..4t+3
    int c0 = 0, c1 = 0, c2 = 0, c3 = 0, psum = 0;
    if (tid < SCAN_T) {
        c0 = lcount[tid * 4 + 0]; c1 = lcount[tid * 4 + 1];
        c2 = lcount[tid * 4 + 2]; c3 = lcount[tid * 4 + 3];
        psum = c0 + c1 + c2 + c3;
    }
    const int lane = tid & 63;
    const int wv = tid >> 6;             // 0..7
    int incl = psum;
#pragma unroll
    for (int o = 1; o < 64; o <<= 1) {
        int n = __shfl_up(incl, o);
        if (lane >= o) incl += n;
    }
    if (lane == 63) wsum[wv] = incl;
    __syncthreads();
    int wpre = 0;
#pragma unroll
    for (int w = 0; w < 7; ++w)
        if (w < wv) wpre += wsum[w];
    int base0 = wpre + incl - psum;       // exclusive prefix of this thread
    if (tid < SCAN_T) {
        lstart[tid * 4 + 0] = base0;
        lstart[tid * 4 + 1] = base0 + c0;
        lstart[tid * 4 + 2] = base0 + c0 + c1;
        lstart[tid * 4 + 3] = base0 + c0 + c1 + c2;
    }
    __syncthreads();

    // reserve global space per bucket
    for (int k = tid; k < NBUCK_PAD; k += SCT) {
        if (lcount[k] > 0) gbase[k] = atomicAdd(&gcursor[k], lcount[k]);
    }

    // stage from registers (no atomics)
#pragma unroll
    for (int t = 0; t < EPT; ++t) {
        if (eb_[t] >= 0) {
            int p = lstart[eb_[t]] + ep_[t];
            sxy[p] = make_int2(ex_[t], ey_[t]);
            sbk[p] = (unsigned short)eb_[t];
        }
    }
    __syncthreads();

    // output: i-ordered -> per-bucket coalesced runs
    for (int i = tid; i < cnt; i += SCT) {
        int b = sbk[i];
        int2 a = sxy[i];
        int dest = gbase[b] + (i - lstart[b]);
        if (dest < (b + 1) * CAP) {
            packed[dest] = a;
        } else {
            int p = atomicAdd(ovf_count, 1);
            if (p < OVF_CAP)
                ovf[p] = make_int4(b * ROWS_PER_BUCKET + (a.x >> COL_BITS),
                                   a.x & COL_MASK, a.y, 0);
        }
    }
}

// 2 blocks per bucket (row halves, 64 rows each, all 64 features), plus
// OVF_BLOCKS trailing drain-role blocks (replace overflow_scatter launch).
// Raw chunk is staged to LDS during the histogram pass -- packed is read
// from global ONCE per block (r11 read it twice). In-LDS counting sort
// (sorted int2 stored directly), then gather with 16-lane row-groups:
// each lane loads uint2 = 4 bf16 features -> one full 128B Y row per
// instruction; 4 register accumulators; float4 out RMW per row.
__global__ __launch_bounds__(256) void bucket_gather_quads(
    const int* __restrict__ gcursor, const int2* __restrict__ packed,
    const unsigned short* __restrict__ Yb, float* __restrict__ out,
    int n_nodes, const int* __restrict__ ovf_count,
    const int4* __restrict__ ovf) {
    __shared__ int2 sraw[MAXB];                    // 16 KB, raw chunk
    __shared__ int2 sxy[MAXB];                     // 16 KB, sorted by row
    __shared__ int hist[ROWS_PER_BUCKET];
    __shared__ int chs[ROWS_PER_BUCKET];
    __shared__ int chc[ROWS_PER_BUCKET];

    int tid = threadIdx.x;
    int nbuck2 = ((n_nodes + 127) >> 7) * 2;

    if (blockIdx.x >= (unsigned)nbuck2) {
        // ---- overflow drain role (normally empty) ----
        int bo = blockIdx.x - nbuck2;
        int cnt = min(*ovf_count, OVF_CAP);
        long long total = (long long)cnt * 64;
        for (long long i = (long long)bo * 256 + tid; i < total;
             i += (long long)OVF_BLOCKS * 256) {
            int e = (int)(i >> 6), f = (int)(i & 63);
            int4 a = ovf[e];
            atomicAdd(&out[(size_t)a.x * 64 + f],
                      __int_as_float(a.z) * bf2f(Yb[(size_t)a.y * 64 + f]));
        }
        return;
    }

    int bucket = blockIdx.x >> 1;
    int rhalf = (blockIdx.x & 1) * 64;   // which 64-row half this block owns
    int fquad = tid & 15;                // features 4*fquad .. 4*fquad+3
    int grp = tid >> 4;                  // 0..15 row-groups
    int s = bucket * CAP;
    int e = min(gcursor[bucket], s + CAP);
    int row0 = bucket * ROWS_PER_BUCKET;
    const uint2* __restrict__ Y64 = (const uint2*)Yb;   // row = 16 uint2

    for (int cb = s; cb < e; cb += MAXB) {
        int cnt = min(MAXB, e - cb);

        if (tid < ROWS_PER_BUCKET) hist[tid] = 0;
        __syncthreads();

        // pass 1: stage raw chunk to LDS + histogram of local rows
        for (int i = tid; i < cnt; i += 256) {
            int2 a = packed[cb + i];
            sraw[i] = a;
            atomicAdd(&hist[a.x >> COL_BITS], 1);
        }
        __syncthreads();

        if (tid < ROWS_PER_BUCKET) chs[tid] = hist[tid];
        __syncthreads();
#pragma unroll
        for (int o = 1; o < ROWS_PER_BUCKET; o <<= 1) {
            int t = 0;
            if (tid < ROWS_PER_BUCKET && tid >= o) t = chs[tid - o];
            __syncthreads();
            if (tid < ROWS_PER_BUCKET) chs[tid] += t;
            __syncthreads();
        }
        if (tid < ROWS_PER_BUCKET) {
            int excl = chs[tid] - hist[tid];
            chs[tid] = excl;
            chc[tid] = excl;
        }
        __syncthreads();

        // pass 2: counting-sort scatter from LDS (no second global read)
        for (int i = tid; i < cnt; i += 256) {
            int2 a = sraw[i];
            int p = atomicAdd(&chc[a.x >> COL_BITS], 1);
            sxy[p] = a;
        }
        __syncthreads();

        // gather: 16 groups x 4 rows; 16 lanes per row, 4 features/lane
        for (int rr = 0; rr < 4; ++rr) {
            int r = rhalf + grp * 4 + rr;
            int rc = hist[r];
            int node = row0 + r;
            if (rc == 0 || node >= n_nodes) continue;
            int rs = chs[r];
            float a0 = 0.f, a1 = 0.f, a2 = 0.f, a3 = 0.f;
            int j = 0;
            for (; j + 4 <= rc; j += 4) {
                int2 e0 = sxy[rs + j + 0], e1 = sxy[rs + j + 1];
                int2 e2 = sxy[rs + j + 2], e3 = sxy[rs + j + 3];
                uint2 u0 = Y64[(size_t)(e0.x & COL_MASK) * 16 + fquad];
                uint2 u1 = Y64[(size_t)(e1.x & COL_MASK) * 16 + fquad];
                uint2 u2 = Y64[(size_t)(e2.x & COL_MASK) * 16 + fquad];
                uint2 u3 = Y64[(size_t)(e3.x & COL_MASK) * 16 + fquad];
                float v0 = __int_as_float(e0.y), v1 = __int_as_float(e1.y);
                float v2 = __int_as_float(e2.y), v3 = __int_as_float(e3.y);
                a0 = fmaf(v0, __uint_as_float(u0.x << 16), a0);
                a1 = fmaf(v0, __uint_as_float(u0.x & 0xFFFF0000u), a1);
                a2 = fmaf(v0, __uint_as_float(u0.y << 16), a2);
                a3 = fmaf(v0, __uint_as_float(u0.y & 0xFFFF0000u), a3);
                a0 = fmaf(v1, __uint_as_float(u1.x << 16), a0);
                a1 = fmaf(v1, __uint_as_float(u1.x & 0xFFFF0000u), a1);
                a2 = fmaf(v1, __uint_as_float(u1.y << 16), a2);
                a3 = fmaf(v1, __uint_as_float(u1.y & 0xFFFF0000u), a3);
                a0 = fmaf(v2, __uint_as_float(u2.x << 16), a0);
                a1 = fmaf(v2, __uint_as_float(u2.x & 0xFFFF0000u), a1);
                a2 = fmaf(v2, __uint_as_float(u2.y << 16), a2);
                a3 = fmaf(v2, __uint_as_float(u2.y & 0xFFFF0000u), a3);
                a0 = fmaf(v3, __uint_as_float(u3.x << 16), a0);
                a1 = fmaf(v3, __uint_as_float(u3.x & 0xFFFF0000u), a1);
                a2 = fmaf(v3, __uint_as_float(u3.y << 16), a2);
                a3 = fmaf(v3, __uint_as_float(u3.y & 0xFFFF0000u), a3);
            }
            for (; j < rc; ++j) {
                int2 e0 = sxy[rs + j];
                uint2 u0 = Y64[(size_t)(e0.x & COL_MASK) * 16 + fquad];
                float v0 = __int_as_float(e0.y);
                a0 = fmaf(v0, __uint_as_float(u0.x << 16), a0);
                a1 = fmaf(v0, __uint_as_float(u0.x & 0xFFFF0000u), a1);
                a2 = fmaf(v0, __uint_as_float(u0.y << 16), a2);
                a3 = fmaf(v0, __uint_as_float(u0.y & 0xFFFF0000u), a3);
            }
            float4* op = (float4*)(out + (size_t)node * 64 + fquad * 4);
            float4 o = *op;
            o.x += a0; o.y += a1; o.z += a2; o.w += a3;
            *op = o;                                 // out holds Z
        }
        __syncthreads();
    }
}

// ---------------- fallback (atomic path) ----------------

__global__ __launch_bounds__(256) void edge_scatter(
    const int* __restrict__ rows, const int* __restrict__ cols,
    const float* __restrict__ vals, const unsigned short* __restrict__ Yb,
    float* __restrict__ out, int n_edges)
{
    int t = blockIdx.x * 256 + threadIdx.x;
    int e = t >> 4;
    int f = (t & 15) << 2;
    if (e >= n_edges) return;
    int r = rows[e];
    int c = cols[e];
    float v = vals[e];
    const unsigned short* y = Yb + (size_t)c * 64 + f;
    float* o = out + (size_t)r * 64 + f;
    atomicAdd(o + 0, v * bf2f(y[0]));
    atomicAdd(o + 1, v * bf2f(y[1]));
    atomicAdd(o + 2, v * bf2f(y[2]));
    atomicAdd(o + 3, v * bf2f(y[3]));
}

extern "C" void kernel_launch(void* const* d_in, const int* in_sizes, int n_in,
                              void* d_out, int out_size, void* d_ws, size_t ws_size,
                              hipStream_t stream) {
    const int*   rows = (const int*)d_in[0];
    const int*   cols = (const int*)d_in[1];
    const float* vals = (const float*)d_in[2];
    const float* X    = (const float*)d_in[3];
    const float* W1   = (const float*)d_in[4];
    const float* b1   = (const float*)d_in[5];
    const float* W2   = (const float*)d_in[6];
    const float* b2   = (const float*)d_in[7];
    float* out = (float*)d_out;

    const int n_edges = in_sizes[0];
    const int n_nodes = in_sizes[3] / 64;
    const int nbuck = (n_nodes + ROWS_PER_BUCKET - 1) / ROWS_PER_BUCKET;

    char* ws = (char*)d_ws;
    size_t o_Yb     = 0;                                    // bf16 Y
    size_t o_packed = o_Yb + (size_t)n_nodes * 64 * 2;      // 16B-aligned (n*128)
    size_t o_ovf    = o_packed + (size_t)NBUCK_PAD * CAP * 8;
    size_t o_gcurs  = o_ovf + (size_t)OVF_CAP * 16;
    size_t o_ovfcnt = o_gcurs + NBUCK_PAD * 4;
    size_t o_wb1    = o_ovfcnt + 16;
    size_t o_wb2    = o_wb1 + 64 * 64 * 2;
    size_t o_bs     = o_wb2 + 64 * 64 * 2;
    size_t need     = o_bs + 64 * 4;

    unsigned short* Yb = (unsigned short*)(ws + o_Yb);

    const bool fastpath =
        ws_size >= need && nbuck <= NBUCK_PAD && n_nodes <= (1 << COL_BITS);

    // Wb/bsum placement: fastpath layout, else right after Yb.
    size_t fb_wb1 = o_Yb + (size_t)n_nodes * 64 * 2;
    unsigned short* Wb1t = (unsigned short*)(ws + (fastpath ? o_wb1 : fb_wb1));
    unsigned short* Wb2t = Wb1t + 64 * 64;
    float* bsum = (float*)(Wb2t + 64 * 64);

    int2* packed  = (int2*)(ws + o_packed);
    int4* ovf     = (int4*)(ws + o_ovf);
    int*  gcursor = fastpath ? (int*)(ws + o_gcurs) : (int*)0;
    int*  ovfcnt  = (int*)(ws + o_ovfcnt);

    int nblocks = (n_nodes + 127) / 128;

    prep<<<16, 256, 0, stream>>>(W1, W2, b1, b2, Wb1t, Wb2t, bsum,
                                 gcursor, fastpath ? ovfcnt : (int*)0);
    node_transform<<<nblocks, 256, 0, stream>>>(X, Wb1t, Wb2t, bsum,
                                                Yb, out, n_nodes);

    if (fastpath) {
        int eb = (n_edges + CHUNK - 1) / CHUNK;
        bin_scatter<<<eb, SCT, 0, stream>>>(rows, cols, vals, gcursor, packed,
                                            ovfcnt, ovf, n_edges);
        bucket_gather_quads<<<nbuck * 2 + OVF_BLOCKS, 256, 0, stream>>>(
            gcursor, packed, Yb, out, n_nodes, ovfcnt, ovf);
    } else {
        long long threads = (long long)n_edges * 16;
        int eblocks = (int)((threads + 255) / 256);
        edge_scatter<<<eblocks, 256, 0, stream>>>(rows, cols, vals, Yb, out, n_edges);
    }
}

// Round 13
// 159.043 us; speedup vs baseline: 1.0417x; 1.0417x over previous
//
#include <hip/hip_runtime.h>

// out = L@(X@W1 + X^2@W2) + X@W1 + b1 + b2
// Y (bf16, ws) = X@W1 + X^2@W2 ; Z = X@W1 + b1 + b2.
// Pipeline (r11 structure -- best measured 155.3us):
//   node_transform (MFMA 16x16x32; W staged per-block into LDS via
//   coalesced float4 reads + one bf16 transpose, fragments = ds_read_b128;
//   folds cursor_init) -> bin_scatter (512 threads, LDS chunk-sort,
//   single-atomic-pass, register-carried edges) -> bucket_gather_quads
//   (2 blocks/bucket row halves; in-LDS counting sort; uint2 = 4x bf16
//   gather loads; register acc; float4 out RMW) -> overflow_scatter.
//
// MEASURED LESSONS:
//  r3/r4: LDS fp32 atomicAdd (plain AND unsafeAtomicAdd -- identical
//    codegen) ~139 cyc/op fully serialized on gfx950. No LDS fp atomics
//    in hot accumulation; counting-sort + register acc wins 13x.
//  r6/r10: per-edge GLOBAL atomics lose BOTH ways -- hot-line atomic-rtn
//    (r6: 83us) AND spread no-return (r10: +25us). Keep per-edge counting
//    in LDS.
//  r8/r9: NT+scatter fusion neutral-negative; 512-thread 1-block/bucket
//    gather slower than 2x256.
//  r11: bin_scatter 256->512 threads (occupancy 12%->~25%) = -5.5us.
//  r12: bundle (prep launch + gather 2nd LDS buffer at 33.5KB) = +10us
//    REGRESSION -- extra launch dependency + gather occupancy 7->4
//    blocks/CU. Reverted; W-load fix now in-kernel, gather untouched.

#define ROWS_PER_BUCKET 128
#define ROW_SHIFT 7
#define NBUCK_PAD 784        // 196*4, covers nbuck=782
#define SCAN_T 196
#define CAP 2048             // per-bucket fixed capacity
#define CHUNK 4096           // edges per bin_scatter block
#define SCT 512              // bin_scatter threads
#define EPT 8                // CHUNK / SCT edges per thread
#define MAXB 2048            // max bucket-chunk held in LDS by gather
#define WSTRIDE 72           // LDS W row stride (16B-aligned, bank-spread)
#define COL_BITS 17
#define COL_MASK 0x1FFFF
#define OVF_CAP 65536

typedef __attribute__((ext_vector_type(8))) short bf16x8;
typedef __attribute__((ext_vector_type(4))) float f32x4;

__device__ __forceinline__ unsigned short f2bf(float x) {
    unsigned u = __float_as_uint(x);
    unsigned r = (u + 0x7FFFu + ((u >> 16) & 1u)) >> 16;   // RNE
    return (unsigned short)r;
}
__device__ __forceinline__ float bf2f(unsigned short h) {
    return __uint_as_float(((unsigned)h) << 16);
}

// MFMA node transform: block = 256 threads = 4 waves, 128 rows/block.
// Wave w: rows base+w*32 .. +31. Frags: A row = lane&15, k = 8*(lane>>4)+j;
// B col = lane&15, same k; D row = 4*(lane>>4)+i, col = lane&15.
// W1/W2 staged once per block into LDS transposed bf16 [col][WSTRIDE]:
// coalesced float4 global reads, one conversion; fragment = ds_read_b128
// (replaces r11's 128 scalar stride-64 global loads + 128 f2bf per thread).
__global__ __launch_bounds__(256) void node_transform(
    const float* __restrict__ X, const float* __restrict__ W1,
    const float* __restrict__ b1, const float* __restrict__ W2,
    const float* __restrict__ b2, unsigned short* __restrict__ Yb,
    float* __restrict__ Z, int n_nodes,
    int* __restrict__ gcursor, int* __restrict__ ovf_count)
{
    __shared__ unsigned short w1s[64 * WSTRIDE];   // 9.2 KB
    __shared__ unsigned short w2s[64 * WSTRIDE];   // 9.2 KB

    const int tid = threadIdx.x;

    // folded cursor_init
    if (gcursor) {
        int gi = blockIdx.x * 256 + tid;
        if (gi < NBUCK_PAD) gcursor[gi] = gi * CAP;
        if (gi == 0) *ovf_count = 0;
    }

    // ---- stage W1/W2 -> LDS, transposed bf16 ----
#pragma unroll
    for (int i = 0; i < 4; ++i) {
        int idx = (tid + 256 * i) * 4;            // 4 consecutive elements
        int k = idx >> 6, col = idx & 63;         // same k, cols col..col+3
        float4 v1 = *(const float4*)(W1 + idx);
        float4 v2 = *(const float4*)(W2 + idx);
        w1s[(col + 0) * WSTRIDE + k] = f2bf(v1.x);
        w1s[(col + 1) * WSTRIDE + k] = f2bf(v1.y);
        w1s[(col + 2) * WSTRIDE + k] = f2bf(v1.z);
        w1s[(col + 3) * WSTRIDE + k] = f2bf(v1.w);
        w2s[(col + 0) * WSTRIDE + k] = f2bf(v2.x);
        w2s[(col + 1) * WSTRIDE + k] = f2bf(v2.y);
        w2s[(col + 2) * WSTRIDE + k] = f2bf(v2.z);
        w2s[(col + 3) * WSTRIDE + k] = f2bf(v2.w);
    }
    __syncthreads();

    const int lane = tid & 63;
    const int wave = tid >> 6;          // 0..3
    const int lg = lane >> 4;           // 0..3
    const int lr = lane & 15;

    const int base = blockIdx.x * 128 + wave * 32;

    // ---- B fragments: one ds_read_b128 each ----
    bf16x8 bw1[2][4];
    bf16x8 bw2[2][4];
#pragma unroll
    for (int ks = 0; ks < 2; ++ks) {
#pragma unroll
        for (int cf = 0; cf < 4; ++cf) {
            const int off = (cf * 16 + lr) * WSTRIDE + ks * 32 + lg * 8;
            bw1[ks][cf] = *(const bf16x8*)(w1s + off);
            bw2[ks][cf] = *(const bf16x8*)(w2s + off);
        }
    }

    f32x4 acc1[2][4];
    f32x4 acc2[2][4];
#pragma unroll
    for (int rf = 0; rf < 2; ++rf)
#pragma unroll
        for (int cf = 0; cf < 4; ++cf) {
            acc1[rf][cf] = (f32x4){0.f, 0.f, 0.f, 0.f};
            acc2[rf][cf] = (f32x4){0.f, 0.f, 0.f, 0.f};
        }

    // ---- main: load A (X rows, coalesced 32B/lane), square, MFMA ----
#pragma unroll
    for (int rf = 0; rf < 2; ++rf) {
        const int row = base + rf * 16 + lr;
        const bool rok = row < n_nodes;
        const float* xp = X + (size_t)row * 64 + lg * 8;
#pragma unroll
        for (int ks = 0; ks < 2; ++ks) {
            float xv[8];
            if (rok) {
                float4 v0 = *(const float4*)(xp + ks * 32);
                float4 v1 = *(const float4*)(xp + ks * 32 + 4);
                xv[0] = v0.x; xv[1] = v0.y; xv[2] = v0.z; xv[3] = v0.w;
                xv[4] = v1.x; xv[5] = v1.y; xv[6] = v1.z; xv[7] = v1.w;
            } else {
#pragma unroll
                for (int j = 0; j < 8; ++j) xv[j] = 0.f;
            }
            bf16x8 a, q;
#pragma unroll
            for (int j = 0; j < 8; ++j) {
                a[j] = (short)f2bf(xv[j]);
                float s = xv[j] * xv[j];
                q[j] = (short)f2bf(s);
            }
#pragma unroll
            for (int cf = 0; cf < 4; ++cf) {
                acc1[rf][cf] = __builtin_amdgcn_mfma_f32_16x16x32_bf16(
                    a, bw1[ks][cf], acc1[rf][cf], 0, 0, 0);
                acc2[rf][cf] = __builtin_amdgcn_mfma_f32_16x16x32_bf16(
                    q, bw2[ks][cf], acc2[rf][cf], 0, 0, 0);
            }
        }
    }

    // ---- epilogue ----
    float bsv[4];
#pragma unroll
    for (int cf = 0; cf < 4; ++cf)
        bsv[cf] = b1[cf * 16 + lr] + b2[cf * 16 + lr];

#pragma unroll
    for (int rf = 0; rf < 2; ++rf) {
#pragma unroll
        for (int i = 0; i < 4; ++i) {
            const int row = base + rf * 16 + lg * 4 + i;
            if (row < n_nodes) {
#pragma unroll
                for (int cf = 0; cf < 4; ++cf) {
                    const float v1 = acc1[rf][cf][i];
                    const float y = v1 + acc2[rf][cf][i];
                    const float z = v1 + bsv[cf];
                    Yb[(size_t)row * 64 + cf * 16 + lr] = f2bf(y);
                    Z[(size_t)row * 64 + cf * 16 + lr] = z;
                }
            }
        }
    }
}

// ---------------- fixed-capacity bucket build ----------------

// LDS-staged binned scatter, single-atomic-pass at 512 threads (r11):
//  pass 1: read each edge ONCE; the LDS histogram atomic's return value is
//          the in-bucket position; edge data stays in registers (EPT=8
//          statically-indexed -> VGPRs).
//  scan:   per-wave __shfl_up inclusive scan + 8-entry cross-wave fixup.
//  stage:  int2 LDS write at lstart[b]+p, no second atomic.
//  out:    i-ordered walk -> coalesced runs into packed[] per bucket.
__global__ __launch_bounds__(512) void bin_scatter(
    const int* __restrict__ rows, const int* __restrict__ cols,
    const float* __restrict__ vals, int* __restrict__ gcursor,
    int2* __restrict__ packed, int* __restrict__ ovf_count,
    int4* __restrict__ ovf, int n_edges) {
    __shared__ int lcount[NBUCK_PAD];              // 3.1 KB
    __shared__ int lstart[NBUCK_PAD];              // 3.1 KB
    __shared__ int gbase[NBUCK_PAD];               // 3.1 KB
    __shared__ int2 sxy[CHUNK];                    // 32 KB
    __shared__ unsigned short sbk[CHUNK];          // 8 KB
    __shared__ int wsum[8];

    int tid = threadIdx.x;
    int eb0 = blockIdx.x * CHUNK;
    int cnt = min(CHUNK, n_edges - eb0);

    for (int k = tid; k < NBUCK_PAD; k += SCT) lcount[k] = 0;
    __syncthreads();

    // pass 1: single read + histogram with position capture
    int eb_[EPT], ep_[EPT], ex_[EPT], ey_[EPT];
#pragma unroll
    for (int t = 0; t < EPT; ++t) {
        int i = tid + SCT * t;
        if (i < cnt) {
            int r = rows[eb0 + i];
            int b = r >> ROW_SHIFT;
            eb_[t] = b;
            ep_[t] = atomicAdd(&lcount[b], 1);
            ex_[t] = ((r & (ROWS_PER_BUCKET - 1)) << COL_BITS) | cols[eb0 + i];
            ey_[t] = __float_as_int(vals[eb0 + i]);
        } else {
            eb_[t] = -1; ep_[t] = 0; ex_[t] = 0; ey_[t] = 0;
        }
    }
    __syncthreads();

    // exclusive scan of lcount: thread t<SCAN_T owns buckets 4t..4t+3
    int c0 = 0, c1 = 0, c2 = 0, c3 = 0, psum = 0;
    if (tid < SCAN_T) {
        c0 = lcount[tid * 4 + 0]; c1 = lcount[tid * 4 + 1];
        c2 = lcount[tid * 4 + 2]; c3 = lcount[tid * 4 + 3];
        psum = c0 + c1 + c2 + c3;
    }
    const int lane = tid & 63;
    const int wv = tid >> 6;             // 0..7
    int incl = psum;
#pragma unroll
    for (int o = 1; o < 64; o <<= 1) {
        int n = __shfl_up(incl, o);
        if (lane >= o) incl += n;
    }
    if (lane == 63) wsum[wv] = incl;
    __syncthreads();
    int wpre = 0;
#pragma unroll
    for (int w = 0; w < 7; ++w)
        if (w < wv) wpre += wsum[w];
    int base0 = wpre + incl - psum;       // exclusive prefix of this thread
    if (tid < SCAN_T) {
        lstart[tid * 4 + 0] = base0;
        lstart[tid * 4 + 1] = base0 + c0;
        lstart[tid * 4 + 2] = base0 + c0 + c1;
        lstart[tid * 4 + 3] = base0 + c0 + c1 + c2;
    }
    __syncthreads();

    // reserve global space per bucket
    for (int k = tid; k < NBUCK_PAD; k += SCT) {
        if (lcount[k] > 0) gbase[k] = atomicAdd(&gcursor[k], lcount[k]);
    }

    // stage from registers (no atomics)
#pragma unroll
    for (int t = 0; t < EPT; ++t) {
        if (eb_[t] >= 0) {
            int p = lstart[eb_[t]] + ep_[t];
            sxy[p] = make_int2(ex_[t], ey_[t]);
            sbk[p] = (unsigned short)eb_[t];
        }
    }
    __syncthreads();

    // output: i-ordered -> per-bucket coalesced runs
    for (int i = tid; i < cnt; i += SCT) {
        int b = sbk[i];
        int2 a = sxy[i];
        int dest = gbase[b] + (i - lstart[b]);
        if (dest < (b + 1) * CAP) {
            packed[dest] = a;
        } else {
            int p = atomicAdd(ovf_count, 1);
            if (p < OVF_CAP)
                ovf[p] = make_int4(b * ROWS_PER_BUCKET + (a.x >> COL_BITS),
                                   a.x & COL_MASK, a.y, 0);
        }
    }
}

// 2 blocks per bucket (row halves, 64 rows each, all 64 features).
// In-LDS counting sort by local row (sorted int2 stored directly), then
// gather with 16-lane row-groups: each lane loads uint2 = 4 bf16 features,
// so one instruction fetches a full 128B Y row; 4 register accumulators per
// lane; float4 out RMW per row. 16 groups x 4 rows per block.
__global__ __launch_bounds__(256) void bucket_gather_quads(
    const int* __restrict__ gcursor, const int2* __restrict__ packed,
    const unsigned short* __restrict__ Yb, float* __restrict__ out,
    int n_nodes) {
    __shared__ int2 sxy[MAXB];                     // 16 KB, sorted by row
    __shared__ int hist[ROWS_PER_BUCKET];
    __shared__ int chs[ROWS_PER_BUCKET];
    __shared__ int chc[ROWS_PER_BUCKET];

    int tid = threadIdx.x;
    int bucket = blockIdx.x >> 1;
    int rhalf = (blockIdx.x & 1) * 64;   // which 64-row half this block owns
    int fquad = tid & 15;                // features 4*fquad .. 4*fquad+3
    int grp = tid >> 4;                  // 0..15 row-groups
    int s = bucket * CAP;
    int e = min(gcursor[bucket], s + CAP);
    int row0 = bucket * ROWS_PER_BUCKET;
    const uint2* __restrict__ Y64 = (const uint2*)Yb;   // row = 16 uint2

    for (int cb = s; cb < e; cb += MAXB) {
        int cnt = min(MAXB, e - cb);

        if (tid < ROWS_PER_BUCKET) hist[tid] = 0;
        __syncthreads();

        // pass 1: histogram of local rows
        for (int i = tid; i < cnt; i += 256)
            atomicAdd(&hist[packed[cb + i].x >> COL_BITS], 1);
        __syncthreads();

        if (tid < ROWS_PER_BUCKET) chs[tid] = hist[tid];
        __syncthreads();
#pragma unroll
        for (int o = 1; o < ROWS_PER_BUCKET; o <<= 1) {
            int t = 0;
            if (tid < ROWS_PER_BUCKET && tid >= o) t = chs[tid - o];
            __syncthreads();
            if (tid < ROWS_PER_BUCKET) chs[tid] += t;
            __syncthreads();
        }
        if (tid < ROWS_PER_BUCKET) {
            int excl = chs[tid] - hist[tid];
            chs[tid] = excl;
            chc[tid] = excl;
        }
        __syncthreads();

        // pass 2: scatter sorted edges directly into LDS (packed is L2-hot)
        for (int i = tid; i < cnt; i += 256) {
            int2 a = packed[cb + i];
            int p = atomicAdd(&chc[a.x >> COL_BITS], 1);
            sxy[p] = a;
        }
        __syncthreads();

        // gather: 16 groups x 4 rows; 16 lanes per row, 4 features/lane
        for (int rr = 0; rr < 4; ++rr) {
            int r = rhalf + grp * 4 + rr;
            int rc = hist[r];
            int node = row0 + r;
            if (rc == 0 || node >= n_nodes) continue;
            int rs = chs[r];
            float a0 = 0.f, a1 = 0.f, a2 = 0.f, a3 = 0.f;
            int j = 0;
            for (; j + 4 <= rc; j += 4) {
                int2 e0 = sxy[rs + j + 0], e1 = sxy[rs + j + 1];
                int2 e2 = sxy[rs + j + 2], e3 = sxy[rs + j + 3];
                uint2 u0 = Y64[(size_t)(e0.x & COL_MASK) * 16 + fquad];
                uint2 u1 = Y64[(size_t)(e1.x & COL_MASK) * 16 + fquad];
                uint2 u2 = Y64[(size_t)(e2.x & COL_MASK) * 16 + fquad];
                uint2 u3 = Y64[(size_t)(e3.x & COL_MASK) * 16 + fquad];
                float v0 = __int_as_float(e0.y), v1 = __int_as_float(e1.y);
                float v2 = __int_as_float(e2.y), v3 = __int_as_float(e3.y);
                a0 = fmaf(v0, __uint_as_float(u0.x << 16), a0);
                a1 = fmaf(v0, __uint_as_float(u0.x & 0xFFFF0000u), a1);
                a2 = fmaf(v0, __uint_as_float(u0.y << 16), a2);
                a3 = fmaf(v0, __uint_as_float(u0.y & 0xFFFF0000u), a3);
                a0 = fmaf(v1, __uint_as_float(u1.x << 16), a0);
                a1 = fmaf(v1, __uint_as_float(u1.x & 0xFFFF0000u), a1);
                a2 = fmaf(v1, __uint_as_float(u1.y << 16), a2);
                a3 = fmaf(v1, __uint_as_float(u1.y & 0xFFFF0000u), a3);
                a0 = fmaf(v2, __uint_as_float(u2.x << 16), a0);
                a1 = fmaf(v2, __uint_as_float(u2.x & 0xFFFF0000u), a1);
                a2 = fmaf(v2, __uint_as_float(u2.y << 16), a2);
                a3 = fmaf(v2, __uint_as_float(u2.y & 0xFFFF0000u), a3);
                a0 = fmaf(v3, __uint_as_float(u3.x << 16), a0);
                a1 = fmaf(v3, __uint_as_float(u3.x & 0xFFFF0000u), a1);
                a2 = fmaf(v3, __uint_as_float(u3.y << 16), a2);
                a3 = fmaf(v3, __uint_as_float(u3.y & 0xFFFF0000u), a3);
            }
            for (; j < rc; ++j) {
                int2 e0 = sxy[rs + j];
                uint2 u0 = Y64[(size_t)(e0.x & COL_MASK) * 16 + fquad];
                float v0 = __int_as_float(e0.y);
                a0 = fmaf(v0, __uint_as_float(u0.x << 16), a0);
                a1 = fmaf(v0, __uint_as_float(u0.x & 0xFFFF0000u), a1);
                a2 = fmaf(v0, __uint_as_float(u0.y << 16), a2);
                a3 = fmaf(v0, __uint_as_float(u0.y & 0xFFFF0000u), a3);
            }
            float4* op = (float4*)(out + (size_t)node * 64 + fquad * 4);
            float4 o = *op;
            o.x += a0; o.y += a1; o.z += a2; o.w += a3;
            *op = o;                                 // out holds Z
        }
        __syncthreads();
    }
}

// drains the (normally empty) overflow list with global atomics
__global__ __launch_bounds__(256) void overflow_scatter(
    const int* __restrict__ ovf_count, const int4* __restrict__ ovf,
    const unsigned short* __restrict__ Yb, float* __restrict__ out) {
    int cnt = min(*ovf_count, OVF_CAP);
    long long total = (long long)cnt * 64;
    for (long long i = blockIdx.x * 256 + threadIdx.x; i < total;
         i += (long long)gridDim.x * 256) {
        int e = (int)(i >> 6), f = (int)(i & 63);
        int4 a = ovf[e];
        atomicAdd(&out[(size_t)a.x * 64 + f],
                  __int_as_float(a.z) * bf2f(Yb[(size_t)a.y * 64 + f]));
    }
}

// ---------------- fallback (atomic path) ----------------

__global__ __launch_bounds__(256) void edge_scatter(
    const int* __restrict__ rows, const int* __restrict__ cols,
    const float* __restrict__ vals, const unsigned short* __restrict__ Yb,
    float* __restrict__ out, int n_edges)
{
    int t = blockIdx.x * 256 + threadIdx.x;
    int e = t >> 4;
    int f = (t & 15) << 2;
    if (e >= n_edges) return;
    int r = rows[e];
    int c = cols[e];
    float v = vals[e];
    const unsigned short* y = Yb + (size_t)c * 64 + f;
    float* o = out + (size_t)r * 64 + f;
    atomicAdd(o + 0, v * bf2f(y[0]));
    atomicAdd(o + 1, v * bf2f(y[1]));
    atomicAdd(o + 2, v * bf2f(y[2]));
    atomicAdd(o + 3, v * bf2f(y[3]));
}

extern "C" void kernel_launch(void* const* d_in, const int* in_sizes, int n_in,
                              void* d_out, int out_size, void* d_ws, size_t ws_size,
                              hipStream_t stream) {
    const int*   rows = (const int*)d_in[0];
    const int*   cols = (const int*)d_in[1];
    const float* vals = (const float*)d_in[2];
    const float* X    = (const float*)d_in[3];
    const float* W1   = (const float*)d_in[4];
    const float* b1   = (const float*)d_in[5];
    const float* W2   = (const float*)d_in[6];
    const float* b2   = (const float*)d_in[7];
    float* out = (float*)d_out;

    const int n_edges = in_sizes[0];
    const int n_nodes = in_sizes[3] / 64;
    const int nbuck = (n_nodes + ROWS_PER_BUCKET - 1) / ROWS_PER_BUCKET;

    char* ws = (char*)d_ws;
    size_t o_Yb     = 0;                                    // bf16 Y
    size_t o_packed = o_Yb + (size_t)n_nodes * 64 * 2;      // 16B-aligned (n*128)
    size_t o_ovf    = o_packed + (size_t)NBUCK_PAD * CAP * 8;
    size_t o_gcurs  = o_ovf + (size_t)OVF_CAP * 16;
    size_t o_ovfcnt = o_gcurs + NBUCK_PAD * 4;
    size_t need     = o_ovfcnt + 16;

    unsigned short* Yb = (unsigned short*)(ws + o_Yb);

    const bool fastpath =
        ws_size >= need && nbuck <= NBUCK_PAD && n_nodes <= (1 << COL_BITS);

    int2* packed  = (int2*)(ws + o_packed);
    int4* ovf     = (int4*)(ws + o_ovf);
    int*  gcursor = fastpath ? (int*)(ws + o_gcurs) : (int*)0;
    int*  ovfcnt  = (int*)(ws + o_ovfcnt);

    int nblocks = (n_nodes + 127) / 128;
    node_transform<<<nblocks, 256, 0, stream>>>(X, W1, b1, W2, b2, Yb, out,
                                                n_nodes, gcursor, ovfcnt);

    if (fastpath) {
        int eb = (n_edges + CHUNK - 1) / CHUNK;
        bin_scatter<<<eb, SCT, 0, stream>>>(rows, cols, vals, gcursor, packed,
                                            ovfcnt, ovf, n_edges);
        bucket_gather_quads<<<nbuck * 2, 256, 0, stream>>>(gcursor, packed, Yb,
                                                           out, n_nodes);
        overflow_scatter<<<128, 256, 0, stream>>>(ovfcnt, ovf, Yb, out);
    } else {
        long long threads = (long long)n_edges * 16;
        int eblocks = (int)((threads + 255) / 256);
        edge_scatter<<<eblocks, 256, 0, stream>>>(rows, cols, vals, Yb, out, n_edges);
    }
}

// Round 14
// 157.204 us; speedup vs baseline: 1.0538x; 1.0117x over previous
//
#include <hip/hip_runtime.h>

// out = L@(X@W1 + X^2@W2) + X@W1 + b1 + b2
// Y (bf16, ws) = X@W1 + X^2@W2 ; Z = X@W1 + b1 + b2.
// Pipeline (r11 structure -- best measured 155.3us):
//   node_transform (MFMA 16x16x32, zero LDS; folds cursor_init) ->
//   bin_scatter (512 threads, LDS chunk-sort, single-atomic-pass,
//   register-carried edges) -> bucket_gather_quads (2 blocks/bucket row
//   halves; in-LDS counting sort with 2-WAVE SHUFFLE SCAN (3 barriers,
//   was 16); uint2 = 4x bf16 gather loads; register acc; float4 out RMW)
//   -> overflow_scatter (empty in practice).
//
// MEASURED LESSONS:
//  r3/r4: LDS fp32 atomicAdd (plain AND unsafeAtomicAdd -- identical
//    codegen) ~139 cyc/op fully serialized on gfx950. No LDS fp atomics
//    in hot accumulation; counting-sort + register acc wins 13x.
//  r6/r10: per-edge GLOBAL atomics lose BOTH ways -- hot-line atomic-rtn
//    (r6: 83us) AND spread no-return (r10: +25us). Keep per-edge counting
//    in LDS.
//  r8/r9: NT+scatter fusion neutral-negative; 512-thread 1-block/bucket
//    gather slower than 2x256.
//  r11: bin_scatter 256->512 threads (occupancy 12%->~25%) = -5.5us.
//  r12/r13: W-load optimizations (prep-kernel transpose AND in-kernel LDS
//    staging) BOTH regressed (+10.4 / +3.7) -- NT's scalar L2-hot W loads
//    were never the bottleneck; added barriers/launches cost more. NT's
//    ~26us is launch+memory-latency floor at 3 blocks/CU.

#define ROWS_PER_BUCKET 128
#define ROW_SHIFT 7
#define NBUCK_PAD 784        // 196*4, covers nbuck=782
#define SCAN_T 196
#define CAP 2048             // per-bucket fixed capacity
#define CHUNK 4096           // edges per bin_scatter block
#define SCT 512              // bin_scatter threads
#define EPT 8                // CHUNK / SCT edges per thread
#define MAXB 2048            // max bucket-chunk held in LDS by gather
#define COL_BITS 17
#define COL_MASK 0x1FFFF
#define OVF_CAP 65536

typedef __attribute__((ext_vector_type(8))) short bf16x8;
typedef __attribute__((ext_vector_type(4))) float f32x4;

__device__ __forceinline__ unsigned short f2bf(float x) {
    unsigned u = __float_as_uint(x);
    unsigned r = (u + 0x7FFFu + ((u >> 16) & 1u)) >> 16;   // RNE
    return (unsigned short)r;
}
__device__ __forceinline__ float bf2f(unsigned short h) {
    return __uint_as_float(((unsigned)h) << 16);
}

// MFMA node transform: block = 256 threads = 4 waves, 128 rows/block.
// Wave w: rows base+w*32 .. +31. Frags: A row = lane&15, k = 8*(lane>>4)+j;
// B col = lane&15, same k; D row = 4*(lane>>4)+i, col = lane&15.
// Also initializes gcursor/ovf_count (dead until bin_scatter launches).
__global__ __launch_bounds__(256) void node_transform(
    const float* __restrict__ X, const float* __restrict__ W1,
    const float* __restrict__ b1, const float* __restrict__ W2,
    const float* __restrict__ b2, unsigned short* __restrict__ Yb,
    float* __restrict__ Z, int n_nodes,
    int* __restrict__ gcursor, int* __restrict__ ovf_count)
{
    const int tid = threadIdx.x;

    // folded cursor_init
    if (gcursor) {
        int gi = blockIdx.x * 256 + tid;
        if (gi < NBUCK_PAD) gcursor[gi] = gi * CAP;
        if (gi == 0) *ovf_count = 0;
    }

    const int lane = tid & 63;
    const int wave = tid >> 6;          // 0..3
    const int lg = lane >> 4;           // 0..3
    const int lr = lane & 15;

    const int base = blockIdx.x * 128 + wave * 32;

    // ---- B fragments in registers: [mat][ks][cf] ----
    bf16x8 bw1[2][4];
    bf16x8 bw2[2][4];
#pragma unroll
    for (int ks = 0; ks < 2; ++ks) {
#pragma unroll
        for (int cf = 0; cf < 4; ++cf) {
            const int col = cf * 16 + lr;
            const int k0 = ks * 32 + lg * 8;
            bf16x8 t1, t2;
#pragma unroll
            for (int j = 0; j < 8; ++j) {
                t1[j] = (short)f2bf(W1[(k0 + j) * 64 + col]);
                t2[j] = (short)f2bf(W2[(k0 + j) * 64 + col]);
            }
            bw1[ks][cf] = t1;
            bw2[ks][cf] = t2;
        }
    }

    f32x4 acc1[2][4];
    f32x4 acc2[2][4];
#pragma unroll
    for (int rf = 0; rf < 2; ++rf)
#pragma unroll
        for (int cf = 0; cf < 4; ++cf) {
            acc1[rf][cf] = (f32x4){0.f, 0.f, 0.f, 0.f};
            acc2[rf][cf] = (f32x4){0.f, 0.f, 0.f, 0.f};
        }

    // ---- main: load A (X rows, coalesced 32B/lane), square, MFMA ----
#pragma unroll
    for (int rf = 0; rf < 2; ++rf) {
        const int row = base + rf * 16 + lr;
        const bool rok = row < n_nodes;
        const float* xp = X + (size_t)row * 64 + lg * 8;
#pragma unroll
        for (int ks = 0; ks < 2; ++ks) {
            float xv[8];
            if (rok) {
                float4 v0 = *(const float4*)(xp + ks * 32);
                float4 v1 = *(const float4*)(xp + ks * 32 + 4);
                xv[0] = v0.x; xv[1] = v0.y; xv[2] = v0.z; xv[3] = v0.w;
                xv[4] = v1.x; xv[5] = v1.y; xv[6] = v1.z; xv[7] = v1.w;
            } else {
#pragma unroll
                for (int j = 0; j < 8; ++j) xv[j] = 0.f;
            }
            bf16x8 a, q;
#pragma unroll
            for (int j = 0; j < 8; ++j) {
                a[j] = (short)f2bf(xv[j]);
                float s = xv[j] * xv[j];
                q[j] = (short)f2bf(s);
            }
#pragma unroll
            for (int cf = 0; cf < 4; ++cf) {
                acc1[rf][cf] = __builtin_amdgcn_mfma_f32_16x16x32_bf16(
                    a, bw1[ks][cf], acc1[rf][cf], 0, 0, 0);
                acc2[rf][cf] = __builtin_amdgcn_mfma_f32_16x16x32_bf16(
                    q, bw2[ks][cf], acc2[rf][cf], 0, 0, 0);
            }
        }
    }

    // ---- epilogue ----
    float bsv[4];
#pragma unroll
    for (int cf = 0; cf < 4; ++cf)
        bsv[cf] = b1[cf * 16 + lr] + b2[cf * 16 + lr];

#pragma unroll
    for (int rf = 0; rf < 2; ++rf) {
#pragma unroll
        for (int i = 0; i < 4; ++i) {
            const int row = base + rf * 16 + lg * 4 + i;
            if (row < n_nodes) {
#pragma unroll
                for (int cf = 0; cf < 4; ++cf) {
                    const float v1 = acc1[rf][cf][i];
                    const float y = v1 + acc2[rf][cf][i];
                    const float z = v1 + bsv[cf];
                    Yb[(size_t)row * 64 + cf * 16 + lr] = f2bf(y);
                    Z[(size_t)row * 64 + cf * 16 + lr] = z;
                }
            }
        }
    }
}

// ---------------- fixed-capacity bucket build ----------------

// LDS-staged binned scatter, single-atomic-pass at 512 threads (r11):
//  pass 1: read each edge ONCE; the LDS histogram atomic's return value is
//          the in-bucket position; edge data stays in registers (EPT=8
//          statically-indexed -> VGPRs).
//  scan:   per-wave __shfl_up inclusive scan + 8-entry cross-wave fixup.
//  stage:  int2 LDS write at lstart[b]+p, no second atomic.
//  out:    i-ordered walk -> coalesced runs into packed[] per bucket.
__global__ __launch_bounds__(512) void bin_scatter(
    const int* __restrict__ rows, const int* __restrict__ cols,
    const float* __restrict__ vals, int* __restrict__ gcursor,
    int2* __restrict__ packed, int* __restrict__ ovf_count,
    int4* __restrict__ ovf, int n_edges) {
    __shared__ int lcount[NBUCK_PAD];              // 3.1 KB
    __shared__ int lstart[NBUCK_PAD];              // 3.1 KB
    __shared__ int gbase[NBUCK_PAD];               // 3.1 KB
    __shared__ int2 sxy[CHUNK];                    // 32 KB
    __shared__ unsigned short sbk[CHUNK];          // 8 KB
    __shared__ int wsum[8];

    int tid = threadIdx.x;
    int eb0 = blockIdx.x * CHUNK;
    int cnt = min(CHUNK, n_edges - eb0);

    for (int k = tid; k < NBUCK_PAD; k += SCT) lcount[k] = 0;
    __syncthreads();

    // pass 1: single read + histogram with position capture
    int eb_[EPT], ep_[EPT], ex_[EPT], ey_[EPT];
#pragma unroll
    for (int t = 0; t < EPT; ++t) {
        int i = tid + SCT * t;
        if (i < cnt) {
            int r = rows[eb0 + i];
            int b = r >> ROW_SHIFT;
            eb_[t] = b;
            ep_[t] = atomicAdd(&lcount[b], 1);
            ex_[t] = ((r & (ROWS_PER_BUCKET - 1)) << COL_BITS) | cols[eb0 + i];
            ey_[t] = __float_as_int(vals[eb0 + i]);
        } else {
            eb_[t] = -1; ep_[t] = 0; ex_[t] = 0; ey_[t] = 0;
        }
    }
    __syncthreads();

    // exclusive scan of lcount: thread t<SCAN_T owns buckets 4t..4t+3
    int c0 = 0, c1 = 0, c2 = 0, c3 = 0, psum = 0;
    if (tid < SCAN_T) {
        c0 = lcount[tid * 4 + 0]; c1 = lcount[tid * 4 + 1];
        c2 = lcount[tid * 4 + 2]; c3 = lcount[tid * 4 + 3];
        psum = c0 + c1 + c2 + c3;
    }
    const int lane = tid & 63;
    const int wv = tid >> 6;             // 0..7
    int incl = psum;
#pragma unroll
    for (int o = 1; o < 64; o <<= 1) {
        int n = __shfl_up(incl, o);
        if (lane >= o) incl += n;
    }
    if (lane == 63) wsum[wv] = incl;
    __syncthreads();
    int wpre = 0;
#pragma unroll
    for (int w = 0; w < 7; ++w)
        if (w < wv) wpre += wsum[w];
    int base0 = wpre + incl - psum;       // exclusive prefix of this thread
    if (tid < SCAN_T) {
        lstart[tid * 4 + 0] = base0;
        lstart[tid * 4 + 1] = base0 + c0;
        lstart[tid * 4 + 2] = base0 + c0 + c1;
        lstart[tid * 4 + 3] = base0 + c0 + c1 + c2;
    }
    __syncthreads();

    // reserve global space per bucket
    for (int k = tid; k < NBUCK_PAD; k += SCT) {
        if (lcount[k] > 0) gbase[k] = atomicAdd(&gcursor[k], lcount[k]);
    }

    // stage from registers (no atomics)
#pragma unroll
    for (int t = 0; t < EPT; ++t) {
        if (eb_[t] >= 0) {
            int p = lstart[eb_[t]] + ep_[t];
            sxy[p] = make_int2(ex_[t], ey_[t]);
            sbk[p] = (unsigned short)eb_[t];
        }
    }
    __syncthreads();

    // output: i-ordered -> per-bucket coalesced runs
    for (int i = tid; i < cnt; i += SCT) {
        int b = sbk[i];
        int2 a = sxy[i];
        int dest = gbase[b] + (i - lstart[b]);
        if (dest < (b + 1) * CAP) {
            packed[dest] = a;
        } else {
            int p = atomicAdd(ovf_count, 1);
            if (p < OVF_CAP)
                ovf[p] = make_int4(b * ROWS_PER_BUCKET + (a.x >> COL_BITS),
                                   a.x & COL_MASK, a.y, 0);
        }
    }
}

// 2 blocks per bucket (row halves, 64 rows each, all 64 features).
// In-LDS counting sort by local row (sorted int2 stored directly). The
// 128-entry offset scan is a 2-WAVE SHUFFLE SCAN (wave 0 rows 0..63,
// wave 1 rows 64..127, one LDS handoff): 3 barriers replace r11's 16.
// Gather: 16-lane row-groups, uint2 = 4 bf16 features/lane -> one full
// 128B Y row per instruction; 4 register accumulators; float4 out RMW.
__global__ __launch_bounds__(256) void bucket_gather_quads(
    const int* __restrict__ gcursor, const int2* __restrict__ packed,
    const unsigned short* __restrict__ Yb, float* __restrict__ out,
    int n_nodes) {
    __shared__ int2 sxy[MAXB];                     // 16 KB, sorted by row
    __shared__ int hist[ROWS_PER_BUCKET];
    __shared__ int chs[ROWS_PER_BUCKET];
    __shared__ int chc[ROWS_PER_BUCKET];
    __shared__ int w0sum;

    int tid = threadIdx.x;
    int bucket = blockIdx.x >> 1;
    int rhalf = (blockIdx.x & 1) * 64;   // which 64-row half this block owns
    int fquad = tid & 15;                // features 4*fquad .. 4*fquad+3
    int grp = tid >> 4;                  // 0..15 row-groups
    int s = bucket * CAP;
    int e = min(gcursor[bucket], s + CAP);
    int row0 = bucket * ROWS_PER_BUCKET;
    const uint2* __restrict__ Y64 = (const uint2*)Yb;   // row = 16 uint2

    for (int cb = s; cb < e; cb += MAXB) {
        int cnt = min(MAXB, e - cb);

        if (tid < ROWS_PER_BUCKET) hist[tid] = 0;
        __syncthreads();

        // pass 1: histogram of local rows
        for (int i = tid; i < cnt; i += 256)
            atomicAdd(&hist[packed[cb + i].x >> COL_BITS], 1);
        __syncthreads();

        // 2-wave shuffle scan over hist[0..128)
        int h = 0, incl = 0;
        if (tid < ROWS_PER_BUCKET) {
            h = hist[tid];
            incl = h;
            const int lane = tid & 63;
#pragma unroll
            for (int o = 1; o < 64; o <<= 1) {
                int n = __shfl_up(incl, o);
                if (lane >= o) incl += n;
            }
            if (tid == 63) w0sum = incl;
        }
        __syncthreads();
        if (tid < ROWS_PER_BUCKET) {
            int excl = incl - h + (tid >= 64 ? w0sum : 0);
            chs[tid] = excl;
            chc[tid] = excl;
        }
        __syncthreads();

        // pass 2: scatter sorted edges directly into LDS (packed is L2-hot)
        for (int i = tid; i < cnt; i += 256) {
            int2 a = packed[cb + i];
            int p = atomicAdd(&chc[a.x >> COL_BITS], 1);
            sxy[p] = a;
        }
        __syncthreads();

        // gather: 16 groups x 4 rows; 16 lanes per row, 4 features/lane
        for (int rr = 0; rr < 4; ++rr) {
            int r = rhalf + grp * 4 + rr;
            int rc = hist[r];
            int node = row0 + r;
            if (rc == 0 || node >= n_nodes) continue;
            int rs = chs[r];
            float a0 = 0.f, a1 = 0.f, a2 = 0.f, a3 = 0.f;
            int j = 0;
            for (; j + 4 <= rc; j += 4) {
                int2 e0 = sxy[rs + j + 0], e1 = sxy[rs + j + 1];
                int2 e2 = sxy[rs + j + 2], e3 = sxy[rs + j + 3];
                uint2 u0 = Y64[(size_t)(e0.x & COL_MASK) * 16 + fquad];
                uint2 u1 = Y64[(size_t)(e1.x & COL_MASK) * 16 + fquad];
                uint2 u2 = Y64[(size_t)(e2.x & COL_MASK) * 16 + fquad];
                uint2 u3 = Y64[(size_t)(e3.x & COL_MASK) * 16 + fquad];
                float v0 = __int_as_float(e0.y), v1 = __int_as_float(e1.y);
                float v2 = __int_as_float(e2.y), v3 = __int_as_float(e3.y);
                a0 = fmaf(v0, __uint_as_float(u0.x << 16), a0);
                a1 = fmaf(v0, __uint_as_float(u0.x & 0xFFFF0000u), a1);
                a2 = fmaf(v0, __uint_as_float(u0.y << 16), a2);
                a3 = fmaf(v0, __uint_as_float(u0.y & 0xFFFF0000u), a3);
                a0 = fmaf(v1, __uint_as_float(u1.x << 16), a0);
                a1 = fmaf(v1, __uint_as_float(u1.x & 0xFFFF0000u), a1);
                a2 = fmaf(v1, __uint_as_float(u1.y << 16), a2);
                a3 = fmaf(v1, __uint_as_float(u1.y & 0xFFFF0000u), a3);
                a0 = fmaf(v2, __uint_as_float(u2.x << 16), a0);
                a1 = fmaf(v2, __uint_as_float(u2.x & 0xFFFF0000u), a1);
                a2 = fmaf(v2, __uint_as_float(u2.y << 16), a2);
                a3 = fmaf(v2, __uint_as_float(u2.y & 0xFFFF0000u), a3);
                a0 = fmaf(v3, __uint_as_float(u3.x << 16), a0);
                a1 = fmaf(v3, __uint_as_float(u3.x & 0xFFFF0000u), a1);
                a2 = fmaf(v3, __uint_as_float(u3.y << 16), a2);
                a3 = fmaf(v3, __uint_as_float(u3.y & 0xFFFF0000u), a3);
            }
            for (; j < rc; ++j) {
                int2 e0 = sxy[rs + j];
                uint2 u0 = Y64[(size_t)(e0.x & COL_MASK) * 16 + fquad];
                float v0 = __int_as_float(e0.y);
                a0 = fmaf(v0, __uint_as_float(u0.x << 16), a0);
                a1 = fmaf(v0, __uint_as_float(u0.x & 0xFFFF0000u), a1);
                a2 = fmaf(v0, __uint_as_float(u0.y << 16), a2);
                a3 = fmaf(v0, __uint_as_float(u0.y & 0xFFFF0000u), a3);
            }
            float4* op = (float4*)(out + (size_t)node * 64 + fquad * 4);
            float4 o = *op;
            o.x += a0; o.y += a1; o.z += a2; o.w += a3;
            *op = o;                                 // out holds Z
        }
        __syncthreads();
    }
}

// drains the (normally empty) overflow list with global atomics
__global__ __launch_bounds__(256) void overflow_scatter(
    const int* __restrict__ ovf_count, const int4* __restrict__ ovf,
    const unsigned short* __restrict__ Yb, float* __restrict__ out) {
    int cnt = min(*ovf_count, OVF_CAP);
    long long total = (long long)cnt * 64;
    for (long long i = blockIdx.x * 256 + threadIdx.x; i < total;
         i += (long long)gridDim.x * 256) {
        int e = (int)(i >> 6), f = (int)(i & 63);
        int4 a = ovf[e];
        atomicAdd(&out[(size_t)a.x * 64 + f],
                  __int_as_float(a.z) * bf2f(Yb[(size_t)a.y * 64 + f]));
    }
}

// ---------------- fallback (atomic path) ----------------

__global__ __launch_bounds__(256) void edge_scatter(
    const int* __restrict__ rows, const int* __restrict__ cols,
    const float* __restrict__ vals, const unsigned short* __restrict__ Yb,
    float* __restrict__ out, int n_edges)
{
    int t = blockIdx.x * 256 + threadIdx.x;
    int e = t >> 4;
    int f = (t & 15) << 2;
    if (e >= n_edges) return;
    int r = rows[e];
    int c = cols[e];
    float v = vals[e];
    const unsigned short* y = Yb + (size_t)c * 64 + f;
    float* o = out + (size_t)r * 64 + f;
    atomicAdd(o + 0, v * bf2f(y[0]));
    atomicAdd(o + 1, v * bf2f(y[1]));
    atomicAdd(o + 2, v * bf2f(y[2]));
    atomicAdd(o + 3, v * bf2f(y[3]));
}

extern "C" void kernel_launch(void* const* d_in, const int* in_sizes, int n_in,
                              void* d_out, int out_size, void* d_ws, size_t ws_size,
                              hipStream_t stream) {
    const int*   rows = (const int*)d_in[0];
    const int*   cols = (const int*)d_in[1];
    const float* vals = (const float*)d_in[2];
    const float* X    = (const float*)d_in[3];
    const float* W1   = (const float*)d_in[4];
    const float* b1   = (const float*)d_in[5];
    const float* W2   = (const float*)d_in[6];
    const float* b2   = (const float*)d_in[7];
    float* out = (float*)d_out;

    const int n_edges = in_sizes[0];
    const int n_nodes = in_sizes[3] / 64;
    const int nbuck = (n_nodes + ROWS_PER_BUCKET - 1) / ROWS_PER_BUCKET;

    char* ws = (char*)d_ws;
    size_t o_Yb     = 0;                                    // bf16 Y
    size_t o_packed = o_Yb + (size_t)n_nodes * 64 * 2;      // 16B-aligned (n*128)
    size_t o_ovf    = o_packed + (size_t)NBUCK_PAD * CAP * 8;
    size_t o_gcurs  = o_ovf + (size_t)OVF_CAP * 16;
    size_t o_ovfcnt = o_gcurs + NBUCK_PAD * 4;
    size_t need     = o_ovfcnt + 16;

    unsigned short* Yb = (unsigned short*)(ws + o_Yb);

    const bool fastpath =
        ws_size >= need && nbuck <= NBUCK_PAD && n_nodes <= (1 << COL_BITS);

    int2* packed  = (int2*)(ws + o_packed);
    int4* ovf     = (int4*)(ws + o_ovf);
    int*  gcursor = fastpath ? (int*)(ws + o_gcurs) : (int*)0;
    int*  ovfcnt  = (int*)(ws + o_ovfcnt);

    int nblocks = (n_nodes + 127) / 128;
    node_transform<<<nblocks, 256, 0, stream>>>(X, W1, b1, W2, b2, Yb, out,
                                                n_nodes, gcursor, ovfcnt);

    if (fastpath) {
        int eb = (n_edges + CHUNK - 1) / CHUNK;
        bin_scatter<<<eb, SCT, 0, stream>>>(rows, cols, vals, gcursor, packed,
                                            ovfcnt, ovf, n_edges);
        bucket_gather_quads<<<nbuck * 2, 256, 0, stream>>>(gcursor, packed, Yb,
                                                           out, n_nodes);
        overflow_scatter<<<128, 256, 0, stream>>>(ovfcnt, ovf, Yb, out);
    } else {
        long long threads = (long long)n_edges * 16;
        int eblocks = (int)((threads + 255) / 256);
        edge_scatter<<<eblocks, 256, 0, stream>>>(rows, cols, vals, Yb, out, n_edges);
    }
}